// Round 2
// baseline (232.059 us; speedup 1.0000x reference)
//
#include <hip/hip_runtime.h>

// Correlation / cost-volume layer, fp32.
// corr[b, dy*9+dx, y, x] = (1/C) * sum_c in1[b,c,y,x] * in2[b,c,y+dy-4,x+dx-4]
// (zero-padded outside the image).
//
// R2: split each y-quad block into two 64-column halves -> 512 blocks
// (2 blocks/CU, 18 waves/CU) so barrier/staging bubbles of one block are
// hidden by the other. LDS 27.6 KB/block, 36 accumulators/thread.
// Block = 576 threads = (ly:4, dy:9, xg:16); each thread: one dy, all 9 dx,
// one float4 x-quad. Channels in chunks of 8 staged to LDS (in2 only;
// in1 straight from global, L1 serves the 9x dy redundancy).

#define MAXD 4
#define ND 9
#define NDISP 81
#define BATCH 8
#define CH 128
#define HH 128
#define WW 128
#define CC 8
#define NCHUNK (CH / CC)
#define TY 4
#define NROW (TY + 2 * MAXD)   // 12 in2 rows per block
#define XW 64                  // output columns per block
#define P2 72                  // staged row: global x in [xbase-4, xbase+68)
#define NT 576                 // 4 * 9 * 16 = 9 waves
#define NQ 18                  // float4 quads per staged row (72/4)

__global__ __launch_bounds__(NT, 5) void corr_kernel(
    const float* __restrict__ in1,
    const float* __restrict__ in2,
    float* __restrict__ out)
{
    __shared__ float s2[NROW * CC * P2];   // 12*8*72*4 B = 27648 B

    const int tid   = threadIdx.x;
    const int b     = blockIdx.x;
    const int y0    = blockIdx.y * TY;
    const int xbase = blockIdx.z * XW;

    // ---- compute-thread mapping ----
    const int ly = tid / (ND * 16);     // 0..3  output row within quad
    const int dy = (tid / 16) % ND;     // 0..8  displacement row
    const int xg = tid & 15;            // 0..15 x-group
    const int x0 = xg * 4;              // local x quad: x0..x0+3
    const int rl = ly + dy;             // LDS row (r = y0+ly+dy-4)

    float acc[ND][4];
    #pragma unroll
    for (int d = 0; d < ND; ++d)
        #pragma unroll
        for (int i = 0; i < 4; ++i) acc[d][i] = 0.0f;

    const float* in2b   = in2 + (size_t)b * CH * HH * WW;
    const float* in1row = in1 + (size_t)b * CH * HH * WW
                              + (size_t)(y0 + ly) * WW + xbase;

    for (int ch = 0; ch < NCHUNK; ++ch) {
        const int c0 = ch * CC;
        __syncthreads();   // previous chunk's compute done

        // ---- stage in2 chunk: 12 rows x 8 ch x 18 float4 (zeros predicated)
        #pragma unroll
        for (int jj = 0; jj < 3; ++jj) {       // 1728 / 576 = exactly 3
            int j   = tid + jj * NT;
            int row = j / (CC * NQ);           // / 144
            int rem = j - row * (CC * NQ);
            int c   = rem / NQ;
            int q   = rem - c * NQ;
            int r   = y0 + row - MAXD;
            int gx  = xbase - MAXD + q * 4;
            float4 v = make_float4(0.0f, 0.0f, 0.0f, 0.0f);
            if (r >= 0 && r < HH && gx >= 0 && gx + 3 < WW)
                v = *(const float4*)(in2b + ((size_t)(c0 + c) * HH + r) * WW + gx);
            *(float4*)&s2[(row * CC + c) * P2 + q * 4] = v;
        }
        __syncthreads();

        // ---- accumulate 8 channels ----
        #pragma unroll
        for (int c = 0; c < CC; ++c) {
            const float* p1 = in1row + (size_t)(c0 + c) * HH * WW;
            float4 a = *(const float4*)(p1 + x0);
            float aa[4] = {a.x, a.y, a.z, a.w};

            const float* s2r = &s2[(rl * CC + c) * P2 + x0];
            float4 b0 = *(const float4*)(s2r);
            float4 b1 = *(const float4*)(s2r + 4);
            float4 b2 = *(const float4*)(s2r + 8);
            float bb[12] = {b0.x, b0.y, b0.z, b0.w,
                            b1.x, b1.y, b1.z, b1.w,
                            b2.x, b2.y, b2.z, b2.w};

            #pragma unroll
            for (int d = 0; d < ND; ++d)
                #pragma unroll
                for (int i = 0; i < 4; ++i)
                    acc[d][i] = fmaf(aa[i], bb[i + d], acc[d][i]);
        }
    }

    // ---- epilogue: mean over C, coalesced float4 stores ----
    const float scale = 1.0f / (float)CH;
    float* outb = out + (size_t)b * NDISP * HH * WW
                      + (size_t)(y0 + ly) * WW + xbase;
    #pragma unroll
    for (int d = 0; d < ND; ++d) {
        float* op = outb + (size_t)(dy * ND + d) * HH * WW;
        float4 v = make_float4(acc[d][0] * scale, acc[d][1] * scale,
                               acc[d][2] * scale, acc[d][3] * scale);
        *(float4*)(op + x0) = v;
    }
}

extern "C" void kernel_launch(void* const* d_in, const int* in_sizes, int n_in,
                              void* d_out, int out_size, void* d_ws, size_t ws_size,
                              hipStream_t stream) {
    const float* in1 = (const float*)d_in[0];
    const float* in2 = (const float*)d_in[1];
    float* out = (float*)d_out;
    dim3 grid(BATCH, HH / TY, WW / XW);
    corr_kernel<<<grid, NT, 0, stream>>>(in1, in2, out);
}

// Round 3
// 220.469 us; speedup vs baseline: 1.0526x; 1.0526x over previous
//
#include <hip/hip_runtime.h>

// Correlation / cost-volume, fp32.
// corr[b, dy*9+dx, y, x] = (1/128) * sum_c in1[b,c,y,x] * in2[b,c,y+dy-4,x+dx-4]
//
// R3: latency-first redesign. No LDS, no barriers. Thread = (ly, dy, xg):
// one dy, all 9 dx, 8 px (x0 = 8*xg). Per channel: 2 in1 quads + 4 in2
// window quads ([x0-4, x0+12)) -> 72 FMAs. Register double-buffer over the
// channel loop keeps ~6 dwordx4 loads in flight per wave at all times.
// Zero-padding handled by redirecting invalid quad pointers to a zeroed
// scratch region with stride 0 -> branchless hot loop.

#define MAXD 4
#define ND 9
#define NDISP 81
#define BATCH 8
#define CH 128
#define HH 128
#define WW 128
#define TY 4
#define NT 576            // (ly:4) x (dy:9) x (xg:16) = 9 full waves

__global__ void zero_ws_kernel(float* ws) {
    ws[threadIdx.x] = 0.0f;       // 64 floats = 256 B of guaranteed zeros
}

__global__ __launch_bounds__(NT) void corr_kernel(
    const float* __restrict__ in1,
    const float* __restrict__ in2,
    const float* __restrict__ zbuf,
    float* __restrict__ out)
{
    const int tid = threadIdx.x;
    const int b   = blockIdx.x;
    const int y0  = blockIdx.y * TY;

    const int ly = tid / (ND * 16);     // 0..3
    const int dy = (tid / 16) % ND;     // 0..8
    const int xg = tid & 15;            // 0..15
    const int x0 = xg * 8;              // 8 output px per thread
    const int y  = y0 + ly;
    const int r  = y + dy - MAXD;       // in2 source row
    const bool rok  = (r >= 0) && (r < HH);
    const bool q0ok = rok && (xg > 0);   // window quad [x0-4, x0)
    const bool q3ok = rok && (xg < 15);  // window quad [x0+8, x0+12)

    const int cs = HH * WW;             // channel stride (floats)

    const float* p1   = in1 + ((size_t)b * CH) * cs + y * WW + x0;
    const float* rowp = in2 + ((size_t)b * CH) * cs + (rok ? r : 0) * WW;
    const float* pl = q0ok ? (rowp + x0 - 4) : zbuf;  // quad 0
    const float* pm = rok  ? (rowp + x0)     : zbuf;  // quads 1,2
    const float* ph = q3ok ? (rowp + x0 + 8) : zbuf;  // quad 3
    const int sl = q0ok ? cs : 0;       // per-channel steps (0 => stay on zeros)
    const int sm = rok  ? cs : 0;
    const int sh = q3ok ? cs : 0;

    float acc[ND][8];
    #pragma unroll
    for (int d = 0; d < ND; ++d)
        #pragma unroll
        for (int i = 0; i < 8; ++i) acc[d][i] = 0.0f;

    auto do_fma = [&](const float4& Aa, const float4& Ab,
                      const float4& Wl, const float4& Wm0,
                      const float4& Wm1, const float4& Wh) {
        float a[8]  = {Aa.x, Aa.y, Aa.z, Aa.w, Ab.x, Ab.y, Ab.z, Ab.w};
        float w[16] = {Wl.x,  Wl.y,  Wl.z,  Wl.w,
                       Wm0.x, Wm0.y, Wm0.z, Wm0.w,
                       Wm1.x, Wm1.y, Wm1.z, Wm1.w,
                       Wh.x,  Wh.y,  Wh.z,  Wh.w};
        #pragma unroll
        for (int d = 0; d < ND; ++d)
            #pragma unroll
            for (int i = 0; i < 8; ++i)
                acc[d][i] = fmaf(a[i], w[i + d], acc[d][i]);
    };

    // ---- software pipeline over channels, depth 1, unroll 2 ----
    float4 A0a, A0b, W0l, W0m0, W0m1, W0h;
    float4 A1a, A1b, W1l, W1m0, W1m1, W1h;

    // prologue: stage0 <- channel 0
    A0a  = *(const float4*)(p1);
    A0b  = *(const float4*)(p1 + 4);
    W0l  = *(const float4*)(pl);
    W0m0 = *(const float4*)(pm);
    W0m1 = *(const float4*)(pm + 4);
    W0h  = *(const float4*)(ph);

    #pragma unroll 1
    for (int c = 0; c < CH - 2; c += 2) {
        // stage1 <- channel c+1
        A1a  = *(const float4*)(p1 + cs);
        A1b  = *(const float4*)(p1 + cs + 4);
        W1l  = *(const float4*)(pl + sl);
        W1m0 = *(const float4*)(pm + sm);
        W1m1 = *(const float4*)(pm + sm + 4);
        W1h  = *(const float4*)(ph + sh);

        do_fma(A0a, A0b, W0l, W0m0, W0m1, W0h);   // channel c

        // advance to c+2, refill stage0
        p1 += 2 * cs;
        pl += 2 * sl;  pm += 2 * sm;  ph += 2 * sh;
        A0a  = *(const float4*)(p1);
        A0b  = *(const float4*)(p1 + 4);
        W0l  = *(const float4*)(pl);
        W0m0 = *(const float4*)(pm);
        W0m1 = *(const float4*)(pm + 4);
        W0h  = *(const float4*)(ph);

        do_fma(A1a, A1b, W1l, W1m0, W1m1, W1h);   // channel c+1
    }

    // epilogue: stage0 holds channel 126; load 127, finish both
    A1a  = *(const float4*)(p1 + cs);
    A1b  = *(const float4*)(p1 + cs + 4);
    W1l  = *(const float4*)(pl + sl);
    W1m0 = *(const float4*)(pm + sm);
    W1m1 = *(const float4*)(pm + sm + 4);
    W1h  = *(const float4*)(ph + sh);
    do_fma(A0a, A0b, W0l, W0m0, W0m1, W0h);
    do_fma(A1a, A1b, W1l, W1m0, W1m1, W1h);

    // ---- store: mean over C ----
    const float scale = 1.0f / (float)CH;
    float* outb = out + (size_t)b * NDISP * cs + (size_t)y * WW + x0;
    #pragma unroll
    for (int d = 0; d < ND; ++d) {
        float* op = outb + (size_t)(dy * ND + d) * cs;
        float4 v0 = make_float4(acc[d][0] * scale, acc[d][1] * scale,
                                acc[d][2] * scale, acc[d][3] * scale);
        float4 v1 = make_float4(acc[d][4] * scale, acc[d][5] * scale,
                                acc[d][6] * scale, acc[d][7] * scale);
        *(float4*)(op)     = v0;
        *(float4*)(op + 4) = v1;
    }
}

extern "C" void kernel_launch(void* const* d_in, const int* in_sizes, int n_in,
                              void* d_out, int out_size, void* d_ws, size_t ws_size,
                              hipStream_t stream) {
    const float* in1 = (const float*)d_in[0];
    const float* in2 = (const float*)d_in[1];
    float* out = (float*)d_out;
    float* zbuf = (float*)d_ws;

    zero_ws_kernel<<<1, 64, 0, stream>>>(zbuf);   // ws is re-poisoned each call
    dim3 grid(BATCH, HH / TY);
    corr_kernel<<<grid, NT, 0, stream>>>(in1, in2, zbuf, out);
}